// Round 2
// baseline (2134.222 us; speedup 1.0000x reference)
//
#include <hip/hip_runtime.h>
#include <hip/hip_bf16.h>
#include <hip/hip_fp8.h>
#include <cstdint>
#include <cstddef>

// Problem constants (from reference)
#define E_ 8
#define H_ 2048
#define I_ 5632
#define N1_ (2 * I_)
#define G_ 128
#define T_ 256
#define RPE 256            // fixed rows per expert (= T_, exact worst case)
#define SLOTS (E_ * RPE)   // 2048

typedef __attribute__((ext_vector_type(4))) float f32x4;
typedef __attribute__((ext_vector_type(8))) __bf16 bf16x8;

// Workspace layout (bytes). Total ~31.5 MB.
#define WS_CNT 0                       // 8 ints
#define WS_TOKEN 64                    // SLOTS ints
#define WS_GATE (64 + SLOTS * 4)       // SLOTS floats
#define WS_A1 32768                    // SLOTS * H_ bf16 = 8,388,608 B
#define WS_A2 (WS_A1 + SLOTS * H_ * 2) // SLOTS * I_ bf16 = 23,068,672 B

__device__ __forceinline__ uint32_t pack_bf16x2(float a, float b) {
  union { float f; uint32_t u; } ua, ub;
  ua.f = a; ub.f = b;
  uint32_t ra = (ua.u + 0x7FFFu + ((ua.u >> 16) & 1u)) >> 16;         // RTNE bf16, low
  uint32_t rb = (ub.u + 0x7FFFu + ((ub.u >> 16) & 1u)) & 0xFFFF0000u; // high
  return ra | rb;
}

__device__ __forceinline__ float fp8_qdq1(float x) {
  x = fminf(fmaxf(x, -448.0f), 448.0f);
  __hip_fp8_e4m3 q(x);  // OCP e4m3fn on gfx950
  return (float)q;
}

// ---------------- routing: softmax top-2 -> fixed-capacity slot lists -------
__global__ void routing_kernel(const float* __restrict__ logits,
                               int* __restrict__ cnt,
                               int* __restrict__ token_of, float* __restrict__ gate_of) {
  __shared__ int s_cnt[E_];
  int t = threadIdx.x;  // one thread per token; blockDim.x == T_ == 256
  if (t < E_) s_cnt[t] = 0;
  __syncthreads();
  float l[E_];
#pragma unroll
  for (int e = 0; e < E_; e++) l[e] = logits[t * E_ + e];
  int i0 = 0;
#pragma unroll
  for (int e = 1; e < E_; e++) if (l[e] > l[i0]) i0 = e;  // ties -> lower idx
  int i1 = (i0 == 0) ? 1 : 0;
#pragma unroll
  for (int e = 0; e < E_; e++) if (e != i0 && l[e] > l[i1]) i1 = e;
  float g0 = 1.0f / (1.0f + expf(l[i1] - l[i0]));  // renormalized top-2 gates
  float g1 = 1.0f - g0;
  int s0 = atomicAdd(&s_cnt[i0], 1);
  int s1 = atomicAdd(&s_cnt[i1], 1);
  token_of[i0 * RPE + s0] = t;  gate_of[i0 * RPE + s0] = g0;
  token_of[i1 * RPE + s1] = t;  gate_of[i1 * RPE + s1] = g1;
  __syncthreads();
  if (t < E_) cnt[t] = s_cnt[t];
  // pad slots (disjoint from scattered ones): token 0, gate 0
  for (int idx = t; idx < SLOTS; idx += 256) {
    int e = idx >> 8, r = idx & (RPE - 1);
    if (r >= s_cnt[e]) { token_of[idx] = 0; gate_of[idx] = 0.0f; }
  }
}

// ---------------- gather + fp8 qdq -> A1 (bf16, zero-padded rows) -----------
__global__ void gather_kernel(const float* __restrict__ hidden,
                              const float* __restrict__ is1,
                              const int* __restrict__ cnt,
                              const int* __restrict__ token_of,
                              __hip_bfloat16* __restrict__ A1) {
  int sg = blockIdx.x;            // slot in [0, SLOTS)
  int e = sg >> 8, r = sg & (RPE - 1);
  bool pad = (r >= cnt[e]);
  uint4 u;
  if (pad) {
    u.x = u.y = u.z = u.w = 0u;
  } else {
    int t = token_of[sg];
    float s1 = is1[e];
    const float4* hp = (const float4*)(hidden + (size_t)t * H_ + threadIdx.x * 8);
    float4 x0 = hp[0], x1 = hp[1];
    float q0 = fp8_qdq1(x0.x / s1), q1 = fp8_qdq1(x0.y / s1);
    float q2 = fp8_qdq1(x0.z / s1), q3 = fp8_qdq1(x0.w / s1);
    float q4 = fp8_qdq1(x1.x / s1), q5 = fp8_qdq1(x1.y / s1);
    float q6 = fp8_qdq1(x1.z / s1), q7 = fp8_qdq1(x1.w / s1);
    u.x = pack_bf16x2(q0, q1); u.y = pack_bf16x2(q2, q3);
    u.z = pack_bf16x2(q4, q5); u.w = pack_bf16x2(q6, q7);
  }
  ((uint4*)(A1 + (size_t)sg * H_))[threadIdx.x] = u;
}

// ---------------- fc1: bf16 MFMA GEMM + fused SwiGLU + qdq -> A2 ------------
// block = 4 waves. waves 0,1 -> up cols [j0, j0+32); waves 2,3 -> gate cols
// [I_+j0, I_+j0+32). Fixed 16 row-chunks per expert -> branch-free K-loop.
__global__ __launch_bounds__(256) void fc1_kernel(
    const int* __restrict__ w1, const float* __restrict__ w1s,
    const float* __restrict__ is1v, const float* __restrict__ is2v,
    const __hip_bfloat16* __restrict__ A1, __hip_bfloat16* __restrict__ A2) {
  int e = blockIdx.y;
  int j0 = blockIdx.x * 32;
  int wave = threadIdx.x >> 6, lane = threadIdx.x & 63;
  int lm = lane & 15, kq = lane >> 4;
  int jj = j0 + (wave & 1) * 16 + lm;
  int n = (wave >> 1) ? (I_ + jj) : jj;
  const int* wcol = w1 + (size_t)e * H_ * N1_ + n;
  const float* scol = w1s + (size_t)e * (H_ / G_) * N1_ + n;
  const __hip_bfloat16* abase = A1 + (size_t)e * RPE * H_;
  f32x4 acc[16];
#pragma unroll
  for (int c = 0; c < 16; c++) acc[c] = (f32x4){0.f, 0.f, 0.f, 0.f};
  for (int kso = 0; kso < H_ / G_; kso++) {      // 16 scale groups
    float sc = scol[(size_t)kso * N1_];
#pragma unroll
    for (int ksi = 0; ksi < 4; ksi++) {          // 4 k32-steps per group
      int kb = (kso * 4 + ksi) * 32 + kq * 8;
      int w[8];
#pragma unroll
      for (int i = 0; i < 8; i++)
        w[i] = __builtin_nontemporal_load(wcol + (size_t)(kb + i) * N1_);
      union { bf16x8 v; uint32_t u[4]; } bf;
#pragma unroll
      for (int i = 0; i < 4; i++)
        bf.u[i] = pack_bf16x2((float)w[2 * i] * sc, (float)w[2 * i + 1] * sc);
#pragma unroll
      for (int c = 0; c < 16; c++) {
        union { bf16x8 v; uint4 u; } a;
        a.u = *(const uint4*)(abase + (size_t)(c * 16 + lm) * H_ + kb);
        acc[c] = __builtin_amdgcn_mfma_f32_16x16x32_bf16(a.v, bf.v, acc[c], 0, 0, 0);
      }
    }
  }
  // epilogue: exchange up/gate through LDS, SwiGLU, qdq(s2) -> A2 bf16
  float s1 = is1v[e], s2 = is2v[e];
  __shared__ float ls[16][68];  // pitch 68 -> only 2-way bank alias (free)
  int colw = (wave >> 1) * 32 + (wave & 1) * 16 + lm;
#pragma unroll
  for (int c = 0; c < 16; c++) {
#pragma unroll
    for (int i = 0; i < 4; i++) ls[kq * 4 + i][colw] = acc[c][i] * s1;
    __syncthreads();
    for (int v = threadIdx.x; v < 512; v += 256) {
      int r = v >> 5, j2 = v & 31;
      float up = ls[r][j2], gt = ls[r][32 + j2];
      float hh = up * (gt / (1.0f + expf(-gt)));  // up * silu(gate)
      float q = fp8_qdq1(hh / s2);
      A2[(size_t)(e * RPE + c * 16 + r) * I_ + (j0 + j2)] = __float2bfloat16(q);
    }
    __syncthreads();
  }
}

// ---------------- fc2: bf16 MFMA GEMM, split-K x4, atomic scatter-add -------
__global__ __launch_bounds__(256) void fc2_kernel(
    const int* __restrict__ w2, const float* __restrict__ w2s,
    const float* __restrict__ is2v, const int* __restrict__ cnt,
    const int* __restrict__ token_of, const float* __restrict__ gate_of,
    const __hip_bfloat16* __restrict__ A2, float* __restrict__ out) {
  int e = blockIdx.y;
  int n0 = blockIdx.x * 64;
  int z = blockIdx.z;                 // split-K slice: 44 k32-steps each
  int wave = threadIdx.x >> 6, lane = threadIdx.x & 63;
  int lm = lane & 15, kq = lane >> 4;
  int n = n0 + wave * 16 + lm;
  const int* wcol = w2 + (size_t)e * I_ * H_ + n;
  const float* scol = w2s + (size_t)e * (I_ / G_) * H_ + n;
  const __hip_bfloat16* abase = A2 + (size_t)e * RPE * I_;
  f32x4 acc[16];
#pragma unroll
  for (int c = 0; c < 16; c++) acc[c] = (f32x4){0.f, 0.f, 0.f, 0.f};
  for (int kso = 0; kso < 11; kso++) {           // 11 scale groups per slice
    float sc = scol[(size_t)(z * 11 + kso) * H_];
#pragma unroll
    for (int ksi = 0; ksi < 4; ksi++) {
      int kb = (z * 44 + kso * 4 + ksi) * 32 + kq * 8;
      int w[8];
#pragma unroll
      for (int i = 0; i < 8; i++)
        w[i] = __builtin_nontemporal_load(wcol + (size_t)(kb + i) * H_);
      union { bf16x8 v; uint32_t u[4]; } bf;
#pragma unroll
      for (int i = 0; i < 4; i++)
        bf.u[i] = pack_bf16x2((float)w[2 * i] * sc, (float)w[2 * i + 1] * sc);
#pragma unroll
      for (int c = 0; c < 16; c++) {
        union { bf16x8 v; uint4 u; } a;
        a.u = *(const uint4*)(abase + (size_t)(c * 16 + lm) * I_ + kb);
        acc[c] = __builtin_amdgcn_mfma_f32_16x16x32_bf16(a.v, bf.v, acc[c], 0, 0, 0);
      }
    }
  }
  float s2 = is2v[e];
  int c_n = cnt[e];
#pragma unroll
  for (int c = 0; c < 16; c++) {
#pragma unroll
    for (int i = 0; i < 4; i++) {
      int slot = c * 16 + kq * 4 + i;
      if (slot < c_n) {   // pad slots: gate==0, skip the atomic entirely
        int t = token_of[e * RPE + slot];
        float gv = gate_of[e * RPE + slot];
        atomicAdd(out + (size_t)t * H_ + n, acc[c][i] * s2 * gv);
      }
    }
  }
}

extern "C" void kernel_launch(void* const* d_in, const int* in_sizes, int n_in,
                              void* d_out, int out_size, void* d_ws, size_t ws_size,
                              hipStream_t stream) {
  const float* hidden = (const float*)d_in[0];
  const float* logits = (const float*)d_in[1];
  const int* w1 = (const int*)d_in[2];
  const int* w2 = (const int*)d_in[3];
  const float* w1s = (const float*)d_in[4];
  const float* w2s = (const float*)d_in[5];
  const float* is1 = (const float*)d_in[6];
  const float* is2 = (const float*)d_in[7];
  float* out = (float*)d_out;
  char* ws = (char*)d_ws;
  int* cnt = (int*)(ws + WS_CNT);
  int* token_of = (int*)(ws + WS_TOKEN);
  float* gate_of = (float*)(ws + WS_GATE);
  __hip_bfloat16* A1 = (__hip_bfloat16*)(ws + WS_A1);
  __hip_bfloat16* A2 = (__hip_bfloat16*)(ws + WS_A2);

  hipMemsetAsync(d_out, 0, (size_t)T_ * H_ * sizeof(float), stream);
  routing_kernel<<<1, 256, 0, stream>>>(logits, cnt, token_of, gate_of);
  gather_kernel<<<SLOTS, 256, 0, stream>>>(hidden, is1, cnt, token_of, A1);
  fc1_kernel<<<dim3(I_ / 32, E_), 256, 0, stream>>>(w1, w1s, is1, is2, A1, A2);
  fc2_kernel<<<dim3(H_ / 64, E_, 4), 256, 0, stream>>>(w2, w2s, is2, cnt, token_of,
                                                       gate_of, A2, out);
}

// Round 3
// 1376.710 us; speedup vs baseline: 1.5502x; 1.5502x over previous
//
#include <hip/hip_runtime.h>
#include <hip/hip_bf16.h>
#include <hip/hip_fp8.h>
#include <cstdint>
#include <cstddef>

// Problem constants (from reference)
#define E_ 8
#define H_ 2048
#define I_ 5632
#define N1_ (2 * I_)
#define G_ 128
#define T_ 256
#define RPE 256            // fixed rows per expert (= T_, exact worst case)
#define SLOTS (E_ * RPE)   // 2048

typedef __attribute__((ext_vector_type(4))) float f32x4;
typedef __attribute__((ext_vector_type(8))) __bf16 bf16x8;

// Workspace layout (bytes). Total ~31.5 MB.
#define WS_CNT 0
#define WS_TOKEN 64
#define WS_GATE (64 + SLOTS * 4)
#define WS_A1 32768                    // SLOTS * H_ bf16 = 8 MB
#define WS_A2 (WS_A1 + SLOTS * H_ * 2) // SLOTS * I_ bf16 = 23 MB

__device__ __forceinline__ uint32_t pack_bf16x2(float a, float b) {
  union { float f; uint32_t u; } ua, ub;
  ua.f = a; ub.f = b;
  uint32_t ra = (ua.u + 0x7FFFu + ((ua.u >> 16) & 1u)) >> 16;         // RTNE bf16, low
  uint32_t rb = (ub.u + 0x7FFFu + ((ub.u >> 16) & 1u)) & 0xFFFF0000u; // high
  return ra | rb;
}

__device__ __forceinline__ float fp8_qdq1(float x) {
  x = fminf(fmaxf(x, -448.0f), 448.0f);
  __hip_fp8_e4m3 q(x);  // OCP e4m3fn on gfx950
  return (float)q;
}

// ---------------- routing: softmax top-2 -> fixed-capacity slot lists -------
__global__ void routing_kernel(const float* __restrict__ logits,
                               int* __restrict__ cnt,
                               int* __restrict__ token_of, float* __restrict__ gate_of) {
  __shared__ int s_cnt[E_];
  int t = threadIdx.x;  // one thread per token; blockDim.x == T_ == 256
  if (t < E_) s_cnt[t] = 0;
  __syncthreads();
  float l[E_];
#pragma unroll
  for (int e = 0; e < E_; e++) l[e] = logits[t * E_ + e];
  int i0 = 0;
#pragma unroll
  for (int e = 1; e < E_; e++) if (l[e] > l[i0]) i0 = e;  // ties -> lower idx
  int i1 = (i0 == 0) ? 1 : 0;
#pragma unroll
  for (int e = 0; e < E_; e++) if (e != i0 && l[e] > l[i1]) i1 = e;
  float g0 = 1.0f / (1.0f + expf(l[i1] - l[i0]));  // renormalized top-2 gates
  float g1 = 1.0f - g0;
  int s0 = atomicAdd(&s_cnt[i0], 1);
  int s1 = atomicAdd(&s_cnt[i1], 1);
  token_of[i0 * RPE + s0] = t;  gate_of[i0 * RPE + s0] = g0;
  token_of[i1 * RPE + s1] = t;  gate_of[i1 * RPE + s1] = g1;
  __syncthreads();
  if (t < E_) cnt[t] = s_cnt[t];
  for (int idx = t; idx < SLOTS; idx += 256) {
    int e = idx >> 8, r = idx & (RPE - 1);
    if (r >= s_cnt[e]) { token_of[idx] = 0; gate_of[idx] = 0.0f; }
  }
}

// ---------------- gather + fp8 qdq -> A1 (bf16, zero-padded rows) -----------
__global__ void gather_kernel(const float* __restrict__ hidden,
                              const float* __restrict__ is1,
                              const int* __restrict__ cnt,
                              const int* __restrict__ token_of,
                              __hip_bfloat16* __restrict__ A1) {
  int sg = blockIdx.x;
  int e = sg >> 8, r = sg & (RPE - 1);
  bool pad = (r >= cnt[e]);
  uint4 u;
  if (pad) {
    u.x = u.y = u.z = u.w = 0u;
  } else {
    int t = token_of[sg];
    float s1 = is1[e];
    const float4* hp = (const float4*)(hidden + (size_t)t * H_ + threadIdx.x * 8);
    float4 x0 = hp[0], x1 = hp[1];
    float q0 = fp8_qdq1(x0.x / s1), q1 = fp8_qdq1(x0.y / s1);
    float q2 = fp8_qdq1(x0.z / s1), q3 = fp8_qdq1(x0.w / s1);
    float q4 = fp8_qdq1(x1.x / s1), q5 = fp8_qdq1(x1.y / s1);
    float q6 = fp8_qdq1(x1.z / s1), q7 = fp8_qdq1(x1.w / s1);
    u.x = pack_bf16x2(q0, q1); u.y = pack_bf16x2(q2, q3);
    u.z = pack_bf16x2(q4, q5); u.w = pack_bf16x2(q6, q7);
  }
  ((uint4*)(A1 + (size_t)sg * H_))[threadIdx.x] = u;
}

// ---------------- fc1: LDS-staged pipelined MFMA GEMM + fused SwiGLU --------
// Block = 4 waves. Waves split M: wave w owns m-chunks 4w..4w+3 (all 64 n).
// n-tile = 32 up cols [j0,j0+32) + 32 gate cols [I_+j0,..+32).
// LDS Bt[buf][kq][n(64)][8 k] bf16: one conflict-free ds_read_b128 per B-frag.
// Depth-2 pipeline: weights for ks+2, A-frags for ks+1 in flight.
__global__ __launch_bounds__(256) void fc1_kernel(
    const int* __restrict__ w1, const float* __restrict__ w1s,
    const float* __restrict__ is1v, const float* __restrict__ is2v,
    const __hip_bfloat16* __restrict__ A1, __hip_bfloat16* __restrict__ A2) {
  __shared__ __hip_bfloat16 Bt[2][4][64][8];  // 8 KB
  const int e = blockIdx.y;
  const int j0 = blockIdx.x * 32;
  const int tid = threadIdx.x;
  const int wave = tid >> 6, lane = tid & 63;
  const int lm = lane & 15, kq = lane >> 4;
  const int sn = lane;          // staging: logical n in [0,64)
  const int kb4 = wave * 4;     // staging: k = kb4 + 16*g + c
  const int gcol = (sn < 32) ? (j0 + sn) : (I_ + j0 + (sn - 32));
  const int* wp = w1 + (size_t)e * H_ * N1_ + gcol;
  const float* sbase = w1s + (size_t)e * (H_ / G_) * N1_ + gcol;
  const __hip_bfloat16* abase = A1 + (size_t)e * RPE * H_;

  f32x4 acc[4][4];
#pragma unroll
  for (int a = 0; a < 4; a++)
#pragma unroll
    for (int b = 0; b < 4; b++) acc[a][b] = (f32x4){0.f, 0.f, 0.f, 0.f};

  // prologue: load ks=0 weights, stage into buf0; load ks=1 weights
  int wA[8], wB[8];
  float scA = sbase[0], scB = scA;  // ks=0,1 are in group 0
#pragma unroll
  for (int g = 0; g < 2; g++)
#pragma unroll
    for (int c = 0; c < 4; c++)
      wA[g * 4 + c] = __builtin_nontemporal_load(wp + (size_t)(kb4 + 16 * g + c) * N1_);
#pragma unroll
  for (int g = 0; g < 2; g++) {
    uint32_t p0 = pack_bf16x2((float)wA[g * 4 + 0] * scA, (float)wA[g * 4 + 1] * scA);
    uint32_t p1 = pack_bf16x2((float)wA[g * 4 + 2] * scA, (float)wA[g * 4 + 3] * scA);
    *(uint2*)&Bt[0][(wave >> 1) + 2 * g][sn][(wave & 1) * 4] = make_uint2(p0, p1);
  }
  wp += (size_t)32 * N1_;
#pragma unroll
  for (int g = 0; g < 2; g++)
#pragma unroll
    for (int c = 0; c < 4; c++)
      wB[g * 4 + c] = __builtin_nontemporal_load(wp + (size_t)(kb4 + 16 * g + c) * N1_);
  wp += (size_t)32 * N1_;  // -> ks=2

  // A prefetch for ks=0
  const __hip_bfloat16* aptr[4];
#pragma unroll
  for (int mj = 0; mj < 4; mj++)
    aptr[mj] = abase + (size_t)((wave * 4 + mj) * 16 + lm) * H_ + kq * 8;
  uint4 afr[4];
#pragma unroll
  for (int mj = 0; mj < 4; mj++) afr[mj] = *(const uint4*)aptr[mj];

  __syncthreads();

  for (int ks = 0; ks < 64; ks++) {
    const int buf = ks & 1;
    int wC[8]; float scC = scB;
    if (ks + 2 < 64) {
      if (((ks + 2) & 3) == 0) scC = sbase[(size_t)((ks + 2) >> 2) * N1_];
#pragma unroll
      for (int g = 0; g < 2; g++)
#pragma unroll
        for (int c = 0; c < 4; c++)
          wC[g * 4 + c] = __builtin_nontemporal_load(wp + (size_t)(kb4 + 16 * g + c) * N1_);
    }
    uint4 anx[4];
    if (ks + 1 < 64) {
#pragma unroll
      for (int mj = 0; mj < 4; mj++)
        anx[mj] = *(const uint4*)(aptr[mj] + (ks + 1) * 32);
    }
#pragma unroll
    for (int f = 0; f < 4; f++) {
      union { uint4 u; bf16x8 v; } bu;
      bu.u = *(const uint4*)&Bt[buf][kq][f * 16 + lm][0];
#pragma unroll
      for (int mj = 0; mj < 4; mj++) {
        union { uint4 u; bf16x8 v; } au;
        au.u = afr[mj];
        acc[mj][f] = __builtin_amdgcn_mfma_f32_16x16x32_bf16(au.v, bu.v, acc[mj][f], 0, 0, 0);
      }
    }
    if (ks + 1 < 64) {
#pragma unroll
      for (int g = 0; g < 2; g++) {
        uint32_t p0 = pack_bf16x2((float)wB[g * 4 + 0] * scB, (float)wB[g * 4 + 1] * scB);
        uint32_t p1 = pack_bf16x2((float)wB[g * 4 + 2] * scB, (float)wB[g * 4 + 3] * scB);
        *(uint2*)&Bt[buf ^ 1][(wave >> 1) + 2 * g][sn][(wave & 1) * 4] = make_uint2(p0, p1);
      }
    }
    __syncthreads();
#pragma unroll
    for (int i = 0; i < 8; i++) wB[i] = wC[i];
    scB = scC;
#pragma unroll
    for (int mj = 0; mj < 4; mj++) afr[mj] = anx[mj];
    wp += (size_t)32 * N1_;
  }

  // epilogue: SwiGLU in registers (wave holds matching up f and gate f+2 cols)
  const float s1 = is1v[e], s2 = is2v[e];
  __hip_bfloat16* a2base = A2 + (size_t)(e * RPE) * I_ + j0;
#pragma unroll
  for (int mj = 0; mj < 4; mj++) {
    int mrow = (wave * 4 + mj) * 16 + kq * 4;
#pragma unroll
    for (int r = 0; r < 4; r++) {
#pragma unroll
      for (int f = 0; f < 2; f++) {
        float up = acc[mj][f][r] * s1;
        float gt = acc[mj][f + 2][r] * s1;
        float h = up * (gt / (1.0f + expf(-gt)));  // up * silu(gate)
        float q = fp8_qdq1(h / s2);
        a2base[(size_t)(mrow + r) * I_ + f * 16 + lm] = __float2bfloat16(q);
      }
    }
  }
}

// ---------------- fc2: same structure, split-K x4, atomic scatter-add -------
__global__ __launch_bounds__(256) void fc2_kernel(
    const int* __restrict__ w2, const float* __restrict__ w2s,
    const float* __restrict__ is2v, const int* __restrict__ cnt,
    const int* __restrict__ token_of, const float* __restrict__ gate_of,
    const __hip_bfloat16* __restrict__ A2, float* __restrict__ out) {
  __shared__ __hip_bfloat16 Bt[2][4][64][8];  // 8 KB
  const int e = blockIdx.y;
  const int n0 = blockIdx.x * 64;
  const int z = blockIdx.z;       // 4 slices * 44 k-steps = 176 = I_/32
  const int tid = threadIdx.x;
  const int wave = tid >> 6, lane = tid & 63;
  const int lm = lane & 15, kq = lane >> 4;
  const int sn = lane;
  const int kb4 = wave * 4;
  const int gcol = n0 + sn;
  const int* wp = w2 + (size_t)e * I_ * H_ + (size_t)(z * 44 * 32) * H_ + gcol;
  const float* sbase = w2s + (size_t)e * (I_ / G_) * H_ + gcol;
  const __hip_bfloat16* abase = A2 + (size_t)e * RPE * I_;

  f32x4 acc[4][4];
#pragma unroll
  for (int a = 0; a < 4; a++)
#pragma unroll
    for (int b = 0; b < 4; b++) acc[a][b] = (f32x4){0.f, 0.f, 0.f, 0.f};

  int wA[8], wB[8];
  float scA = sbase[(size_t)(z * 11) * H_], scB = scA;
#pragma unroll
  for (int g = 0; g < 2; g++)
#pragma unroll
    for (int c = 0; c < 4; c++)
      wA[g * 4 + c] = __builtin_nontemporal_load(wp + (size_t)(kb4 + 16 * g + c) * H_);
#pragma unroll
  for (int g = 0; g < 2; g++) {
    uint32_t p0 = pack_bf16x2((float)wA[g * 4 + 0] * scA, (float)wA[g * 4 + 1] * scA);
    uint32_t p1 = pack_bf16x2((float)wA[g * 4 + 2] * scA, (float)wA[g * 4 + 3] * scA);
    *(uint2*)&Bt[0][(wave >> 1) + 2 * g][sn][(wave & 1) * 4] = make_uint2(p0, p1);
  }
  wp += (size_t)32 * H_;
#pragma unroll
  for (int g = 0; g < 2; g++)
#pragma unroll
    for (int c = 0; c < 4; c++)
      wB[g * 4 + c] = __builtin_nontemporal_load(wp + (size_t)(kb4 + 16 * g + c) * H_);
  wp += (size_t)32 * H_;

  const __hip_bfloat16* aptr[4];
#pragma unroll
  for (int mj = 0; mj < 4; mj++)
    aptr[mj] = abase + (size_t)((wave * 4 + mj) * 16 + lm) * I_ + (size_t)z * 44 * 32 + kq * 8;
  uint4 afr[4];
#pragma unroll
  for (int mj = 0; mj < 4; mj++) afr[mj] = *(const uint4*)aptr[mj];

  __syncthreads();

  for (int ks = 0; ks < 44; ks++) {
    const int buf = ks & 1;
    int wC[8]; float scC = scB;
    if (ks + 2 < 44) {
      if (((ks + 2) & 3) == 0) scC = sbase[(size_t)(z * 11 + ((ks + 2) >> 2)) * H_];
#pragma unroll
      for (int g = 0; g < 2; g++)
#pragma unroll
        for (int c = 0; c < 4; c++)
          wC[g * 4 + c] = __builtin_nontemporal_load(wp + (size_t)(kb4 + 16 * g + c) * H_);
    }
    uint4 anx[4];
    if (ks + 1 < 44) {
#pragma unroll
      for (int mj = 0; mj < 4; mj++)
        anx[mj] = *(const uint4*)(aptr[mj] + (ks + 1) * 32);
    }
#pragma unroll
    for (int f = 0; f < 4; f++) {
      union { uint4 u; bf16x8 v; } bu;
      bu.u = *(const uint4*)&Bt[buf][kq][f * 16 + lm][0];
#pragma unroll
      for (int mj = 0; mj < 4; mj++) {
        union { uint4 u; bf16x8 v; } au;
        au.u = afr[mj];
        acc[mj][f] = __builtin_amdgcn_mfma_f32_16x16x32_bf16(au.v, bu.v, acc[mj][f], 0, 0, 0);
      }
    }
    if (ks + 1 < 44) {
#pragma unroll
      for (int g = 0; g < 2; g++) {
        uint32_t p0 = pack_bf16x2((float)wB[g * 4 + 0] * scB, (float)wB[g * 4 + 1] * scB);
        uint32_t p1 = pack_bf16x2((float)wB[g * 4 + 2] * scB, (float)wB[g * 4 + 3] * scB);
        *(uint2*)&Bt[buf ^ 1][(wave >> 1) + 2 * g][sn][(wave & 1) * 4] = make_uint2(p0, p1);
      }
    }
    __syncthreads();
#pragma unroll
    for (int i = 0; i < 8; i++) wB[i] = wC[i];
    scB = scC;
#pragma unroll
    for (int mj = 0; mj < 4; mj++) afr[mj] = anx[mj];
    wp += (size_t)32 * H_;
  }

  const float s2 = is2v[e];
  const int c_n = cnt[e];
#pragma unroll
  for (int mj = 0; mj < 4; mj++) {
    int sl0 = (wave * 4 + mj) * 16 + kq * 4;
#pragma unroll
    for (int r = 0; r < 4; r++) {
      int slot = sl0 + r;
      if (slot < c_n) {
        int t = token_of[e * RPE + slot];
        float gv = gate_of[e * RPE + slot] * s2;
#pragma unroll
        for (int f = 0; f < 4; f++)
          atomicAdd(out + (size_t)t * H_ + n0 + f * 16 + lm, acc[mj][f][r] * gv);
      }
    }
  }
}

extern "C" void kernel_launch(void* const* d_in, const int* in_sizes, int n_in,
                              void* d_out, int out_size, void* d_ws, size_t ws_size,
                              hipStream_t stream) {
  const float* hidden = (const float*)d_in[0];
  const float* logits = (const float*)d_in[1];
  const int* w1 = (const int*)d_in[2];
  const int* w2 = (const int*)d_in[3];
  const float* w1s = (const float*)d_in[4];
  const float* w2s = (const float*)d_in[5];
  const float* is1 = (const float*)d_in[6];
  const float* is2 = (const float*)d_in[7];
  float* out = (float*)d_out;
  char* ws = (char*)d_ws;
  int* cnt = (int*)(ws + WS_CNT);
  int* token_of = (int*)(ws + WS_TOKEN);
  float* gate_of = (float*)(ws + WS_GATE);
  __hip_bfloat16* A1 = (__hip_bfloat16*)(ws + WS_A1);
  __hip_bfloat16* A2 = (__hip_bfloat16*)(ws + WS_A2);

  hipMemsetAsync(d_out, 0, (size_t)T_ * H_ * sizeof(float), stream);
  routing_kernel<<<1, 256, 0, stream>>>(logits, cnt, token_of, gate_of);
  gather_kernel<<<SLOTS, 256, 0, stream>>>(hidden, is1, cnt, token_of, A1);
  fc1_kernel<<<dim3(I_ / 32, E_), 256, 0, stream>>>(w1, w1s, is1, is2, A1, A2);
  fc2_kernel<<<dim3(H_ / 64, E_, 4), 256, 0, stream>>>(w2, w2s, is2, cnt, token_of,
                                                       gate_of, A2, out);
}